// Round 1
// baseline (41.858 us; speedup 1.0000x reference)
//
#include <hip/hip_runtime.h>
#include <hip/hip_bf16.h>

// Problem constants (fixed by the reference):
//   B=8192 samples, D=1024 features, C=90 classes, K=16 sub-centers.
// Only the label-gathered distances d_lab[i,k] = 1 - <x_i, centers[labels_i, k]>
// are needed; the full [B,C,K] einsum in the reference is dead except for that
// gather. Per sample: 16 dots of length 1024, then a scalar epilogue.

#define B_SAMP 8192
#define D_DIM  1024
#define K_SUB  16
#define F4_PER_ROW 256     // 1024 floats / 4

// One wave (64 lanes) per sample; 4 waves (256 threads) per block.
// Each lane owns 16 floats of the x row (4x float4, lane-contiguous per j).
__global__ __launch_bounds__(256) void loss_main(
    const float* __restrict__ x,
    const int*   __restrict__ labels,
    const float* __restrict__ centers,
    float*       __restrict__ block_partials)
{
    const int wave = threadIdx.x >> 6;
    const int lane = threadIdx.x & 63;
    const int i    = blockIdx.x * 4 + wave;   // sample index, grid sized exactly

    const float4* xv = reinterpret_cast<const float4*>(x) + (size_t)i * F4_PER_ROW;
    float4 xr[4];
#pragma unroll
    for (int j = 0; j < 4; ++j) xr[j] = xv[j * 64 + lane];

    const int c = labels[i];
    const float4* cb = reinterpret_cast<const float4*>(centers)
                       + (size_t)c * (K_SUB * F4_PER_ROW);

    float acc[K_SUB];
#pragma unroll
    for (int k = 0; k < K_SUB; ++k) {
        float s = 0.0f;
#pragma unroll
        for (int j = 0; j < 4; ++j) {
            float4 cv = cb[k * F4_PER_ROW + j * 64 + lane];
            s = fmaf(xr[j].x, cv.x, s);
            s = fmaf(xr[j].y, cv.y, s);
            s = fmaf(xr[j].z, cv.z, s);
            s = fmaf(xr[j].w, cv.w, s);
        }
        acc[k] = s;
    }

    // Butterfly-reduce each of the 16 partial dots across the 64 lanes.
#pragma unroll
    for (int k = 0; k < K_SUB; ++k) {
        float v = acc[k];
#pragma unroll
        for (int off = 32; off > 0; off >>= 1)
            v += __shfl_xor(v, off, 64);
        acc[k] = v;   // every lane now holds the full dot product
    }

    // Scalar epilogue (redundant on all lanes; ~60 VALU ops, negligible).
    float d[K_SUB];
    float S = 0.0f;
#pragma unroll
    for (int k = 0; k < K_SUB; ++k) { d[k] = 1.0f - acc[k]; S += d[k]; }

    int   m  = 0;
    float dm = d[0];
#pragma unroll
    for (int k = 1; k < K_SUB; ++k) {
        if (d[k] < dm) { dm = d[k]; m = k; }   // strict < => first min, matches jnp.argmin
    }

    const float inv = 1.0f / S;
    float loss = dm * dm * inv;                 // term1
#pragma unroll
    for (int k = 0; k < K_SUB; ++k) {
        if (k != m) loss += (1.0f - d[k] * inv) * d[k];   // term2
    }

    // Block partial: 4 per-sample losses -> one float per block (deterministic).
    __shared__ float ls[4];
    if (lane == 0) ls[wave] = loss;
    __syncthreads();
    if (threadIdx.x == 0)
        block_partials[blockIdx.x] = ls[0] + ls[1] + ls[2] + ls[3];
}

// Deterministic final reduction of 2048 block partials -> mean.
__global__ __launch_bounds__(256) void reduce_final(
    const float* __restrict__ block_partials,
    float*       __restrict__ out)
{
    const int tid = threadIdx.x;
    float s = 0.0f;
    for (int i = tid; i < (B_SAMP / 4); i += 256) s += block_partials[i];
#pragma unroll
    for (int off = 32; off > 0; off >>= 1)
        s += __shfl_xor(s, off, 64);
    __shared__ float w[4];
    if ((tid & 63) == 0) w[tid >> 6] = s;
    __syncthreads();
    if (tid == 0)
        out[0] = (w[0] + w[1] + w[2] + w[3]) * (1.0f / (float)B_SAMP);
}

extern "C" void kernel_launch(void* const* d_in, const int* in_sizes, int n_in,
                              void* d_out, int out_size, void* d_ws, size_t ws_size,
                              hipStream_t stream)
{
    const float* x       = (const float*)d_in[0];
    const int*   labels  = (const int*)  d_in[1];
    const float* centers = (const float*)d_in[2];
    float*       out     = (float*)d_out;
    float*       ws      = (float*)d_ws;   // 2048 floats of block partials

    loss_main<<<B_SAMP / 4, 256, 0, stream>>>(x, labels, centers, ws);
    reduce_final<<<1, 256, 0, stream>>>(ws, out);
}